// Round 12
// baseline (877.217 us; speedup 1.0000x reference)
//
#include <hip/hip_runtime.h>
#include <math.h>

constexpr int NB  = 256;
constexpr int NS  = 8;
constexpr int NC  = 8;
constexpr int NH  = 501;
constexpr int NL  = 56;
constexpr int NH2 = 1002;
constexpr int NH3 = 1503;
constexpr int NH4 = 2004;
constexpr int KP  = 1024;   // PHYSICAL trio K: 2 segs (hi|lo). Logical K=1536 via remap:
                            //   weights (hi,hi,lo): kA = k<512 ? k : k-512
                            //   B slabs (hi,lo,hi): kB = k<1024 ? k : k-1024
constexpr int KG  = 1536;   // giT stride (3 distinct gates r,z,n — NOT a trio)
constexpr int KE  = 512;    // fp16 snapshot K
constexpr int KA  = 1024;   // edge GEMM K ([hv ; nhs_j])
constexpr int HV  = 512 * 256;

typedef unsigned short u16;
typedef short bf16x8v __attribute__((ext_vector_type(8)));
typedef _Float16 f16x8v __attribute__((ext_vector_type(8)));
typedef _Float16 f16x4v __attribute__((ext_vector_type(4)));
typedef float f32x4 __attribute__((ext_vector_type(4)));

__device__ __forceinline__ float sigf(float x) { return 1.0f / (1.0f + __expf(-x)); }
__device__ __forceinline__ float tanh2(float x) { return 2.0f * sigf(2.0f * x) - 1.0f; }

__device__ __forceinline__ u16 f2bf(float x) {
  union { float f; unsigned u; } c; c.f = x;
  unsigned r = (c.u + 0x7fffu + ((c.u >> 16) & 1u)) >> 16;
  return (u16)r;
}
__device__ __forceinline__ float bf2f(u16 h) {
  union { float f; unsigned u; } c; c.u = ((unsigned)h) << 16; return c.f;
}

__device__ __forceinline__ f32x4 mfma_bf(bf16x8v a, bf16x8v b, f32x4 c) {
  return __builtin_amdgcn_mfma_f32_16x16x32_bf16(a, b, c, 0, 0, 0);
}
__device__ __forceinline__ f32x4 mfma_h(f16x8v a, f16x8v b, f32x4 c) {
  return __builtin_amdgcn_mfma_f32_16x16x32_f16(a, b, c, 0, 0, 0);
}

// 2-seg trio store: (hi | lo). Logical seg 3 (hi) is read via address remap.
__device__ __forceinline__ void storeTrio(u16* __restrict__ T, int b, int h0, const float v[4]) {
  size_t base = (size_t)b * KP;
  if (h0 + 3 < NH) {
    ushort4 hi4, lo4;
    u16 hi, lo;
    hi = f2bf(v[0]); lo = f2bf(v[0] - bf2f(hi)); hi4.x = hi; lo4.x = lo;
    hi = f2bf(v[1]); lo = f2bf(v[1] - bf2f(hi)); hi4.y = hi; lo4.y = lo;
    hi = f2bf(v[2]); lo = f2bf(v[2] - bf2f(hi)); hi4.z = hi; lo4.z = lo;
    hi = f2bf(v[3]); lo = f2bf(v[3] - bf2f(hi)); hi4.w = hi; lo4.w = lo;
    *(ushort4*)&T[base + h0]       = hi4;
    *(ushort4*)&T[base + 512 + h0] = lo4;
  } else {
    for (int r = 0; r < 4; ++r) {
      int h = h0 + r;
      if (h < NH) {
        u16 hi = f2bf(v[r]); u16 lo = f2bf(v[r] - bf2f(hi));
        T[base + h] = hi; T[base + 512 + h] = lo;
      }
    }
  }
}

// ---------------- pack ----------------
// rows: [0,1024) Wgm 2-seg (gate 0..511, map 512..1023); [1024,2560) Whh 2-seg (r,z,n);
// [2560,3584) Wav1 2-seg; [3584,5632) Wlr fp16 K=1024 ([left | right] of ae_w1)
__global__ __launch_bounds__(256) void kPack(
    const float* __restrict__ gate_w, const float* __restrict__ map_w,
    const float* __restrict__ w_hh, const float* __restrict__ av_w1,
    const float* __restrict__ ae_w1,
    u16* __restrict__ Wgm, u16* __restrict__ Whh, u16* __restrict__ Wav1,
    _Float16* __restrict__ Wlr) {
  int r = blockIdx.x;
  if (r < 3584) {
    for (int k = threadIdx.x; k < 512; k += 256) {
      float v = 0.f; u16* dst; int rr;
      if (r < 1024) {
        int h = (r < 512) ? r : r - 512;
        if (h < NH && k < NH) v = (r < 512) ? gate_w[h * NH + k] : map_w[h * NH + k];
        dst = Wgm; rr = r;
      } else if (r < 2560) {
        rr = r - 1024; int g = rr >> 9, h = rr & 511;
        if (h < NH && k < NH) v = w_hh[((size_t)g * NH + h) * NH + k];
        dst = Whh;
      } else {
        rr = r - 2560;
        if (rr < NH2 && k < NH) v = av_w1[(size_t)rr * NH + k];
        dst = Wav1;
      }
      u16 hi = f2bf(v); u16 lo = f2bf(v - bf2f(hi));
      dst[(size_t)rr * KP + k] = hi;
      dst[(size_t)rr * KP + 512 + k] = lo;
    }
  } else {
    int m = r - 3584;
    for (int k = threadIdx.x; k < KA; k += 256) {
      float v = 0.f;
      if (m < NH4) {
        if (k < 512) { if (k < NH) v = ae_w1[(size_t)m * NH2 + k]; }
        else { int kk = k - 512; if (kk < NH) v = ae_w1[(size_t)m * NH2 + NH + kk]; }
      }
      Wlr[(size_t)m * KA + k] = (_Float16)v;
    }
  }
}

// ---------------- merged init ----------------
// blocks: [0,64) out0 ; [64,75) trio pad (11 slabs) ; [75,103) Xe pad (28) ;
// [103,110) Xn pad (7) ; [110,366) lin1 (col per block) ; [366,617) giAll (6 rows/blk)
__global__ __launch_bounds__(256) void kInit(
    float* __restrict__ out0, const float* __restrict__ ae_b2,
    u16* __restrict__ trio, _Float16* __restrict__ Xe, _Float16* __restrict__ Xn,
    const float* __restrict__ z, const float* __restrict__ lin1_w,
    const float* __restrict__ lin1_b, float* __restrict__ g0,
    const float* __restrict__ ne, const float* __restrict__ w_ih,
    const float* __restrict__ b_ih, float* __restrict__ giN, float* __restrict__ giT) {
  int blk = blockIdx.x, t = threadIdx.x;
  if (blk < 64) {
    int e = blk * 256 + t;
    int b = e >> 6, r = e & 63;
    int i = r >> 3, jj = r & 7;
    out0[b * 64 + i * 8 + jj] = (jj < i) ? ae_b2[0] : 0.f;
  } else if (blk < 75) {
    u16* T = trio + (size_t)(blk - 64) * ((size_t)NB * KP) + (size_t)t * KP;
#pragma unroll
    for (int seg = 0; seg < 2; ++seg)
      for (int h = NH; h < 512; ++h) T[seg * 512 + h] = 0;
  } else if (blk < 103) {
    _Float16* X = Xe + (size_t)(blk - 75) * NB * KE + (size_t)t * KE;
    for (int h = NH; h < 512; ++h) X[h] = (_Float16)0.f;
  } else if (blk < 110) {
    _Float16* X = Xn + (size_t)(blk - 103) * NB * KE + (size_t)t * KE;
    for (int h = NH; h < 512; ++h) X[h] = (_Float16)0.f;
  } else if (blk < 366) {
    int b = blk - 110;
    const float* zr = z + (size_t)b * NL;
    for (int h = t; h < NH; h += 256) {
      const float* wr = lin1_w + (size_t)h * NL;
      float acc = lin1_b[h];
#pragma unroll
      for (int l = 0; l < NL; ++l) acc += zr[l] * wr[l];
      g0[h * NB + b] = acc;
      u16 hi = f2bf(acc), lo = f2bf(acc - bf2f(hi));
      trio[(size_t)b * KP + h] = hi;
      trio[(size_t)b * KP + 512 + h] = lo;
    }
  } else {
    int r0 = (blk - 366) * 6, b = t;
    for (int rr = 0; rr < 6; ++rr) {
      int r = r0 + rr;
      if (r >= NH3) break;
      int g = (r >= NH2) ? 2 : ((r >= NH) ? 1 : 0);
      int h = r - g * NH;
      float wv[8];
#pragma unroll
      for (int c = 0; c < 8; ++c) wv[c] = w_ih[r * NC + c];
      float bb = b_ih[r];
      for (int idx = 0; idx < 8; ++idx) {
        float acc = bb;
#pragma unroll
        for (int c = 0; c < 8; ++c) acc += ne[b * 64 + idx * 8 + c] * wv[c];
        giN[((size_t)idx * NH3 + r) * NB + b] = acc;
        giT[((size_t)idx * NB + b) * KG + g * 512 + h] = acc;
      }
    }
  }
}

// ---------------- loop kernels ----------------
// 512 threads / 8 waves; logical K=1536 split 8x192/wave, 2-seg physical layout.
// ALL GEMM operands (A and B) register-batch-prefetched before the MFMA chain;
// epilogue operands hoisted before it too (maximize cold-miss MLP post-boundary).

// kGMT: transition i -> i+1.
__global__ __launch_bounds__(512) void kGMT(
    const u16* __restrict__ Wgm, const u16* __restrict__ Bsrc,
    float* __restrict__ PcO, float* __restrict__ QcO,
    const float* __restrict__ dep, const float* __restrict__ gate_b,
    const float* __restrict__ map_b, float* __restrict__ RS, u16* __restrict__ hinT,
    const float* __restrict__ giT, const float* __restrict__ b_hh,
    _Float16* __restrict__ Xe0, int index) {
  __shared__ f32x4 red[8 * 4 * 64];
  const int b = blockIdx.x, t = threadIdx.x, w = t >> 6, l = t & 63;
  const int quad = l >> 4, lan = l & 15;
  const int ht = b & 31, ct = b >> 5;
  const u16* Ag = Wgm + (size_t)(ht * 16 + lan) * KP;
  const u16* Am = Wgm + (size_t)(512 + ht * 16 + lan) * KP;
  const u16* B0 = Bsrc + (size_t)(ct * 32 + lan) * KP;
  const u16* B1 = Bsrc + (size_t)(ct * 32 + 16 + lan) * KP;
  const int kb = w * 192 + quad * 8;
  bf16x8v bg[6], bh[6], ag[6], am[6];
#pragma unroll
  for (int ks = 0; ks < 6; ++ks) {
    int k = kb + ks * 32;
    int kB = (k < 1024) ? k : k - 1024;
    int kA = (k < 512) ? k : k - 512;
    bg[ks] = *(const bf16x8v*)&B0[kB];
    bh[ks] = *(const bf16x8v*)&B1[kB];
    ag[ks] = *(const bf16x8v*)&Ag[kA];
    am[ks] = *(const bf16x8v*)&Am[kA];
  }
  // epilogue operand hoist
  const int ec = ct * 32 + (w & 1) * 16 + lan;   // ns = w for w<2
  const int eh0 = ht * 16 + quad * 4;
  float e_dj = 0.f, e_gb[4], e_mb[4];
  float x_g[12], x_b[12];
  if (w < 2) {
    e_dj = dep[ec * 64 + index * 8 + (index - 1)];
#pragma unroll
    for (int r = 0; r < 4; ++r) {
      int h = eh0 + r;
      bool ok = h < NH;
      e_gb[r] = ok ? gate_b[h] : 0.f;
      e_mb[r] = ok ? map_b[h] : 0.f;
    }
  } else if (w < 4) {
    int t2 = t - 128;
    int xc = ct * 32 + (t2 & 31);
    int hb = t2 >> 5;
    const float* g = giT + ((size_t)index * NB + xc) * KG;
#pragma unroll
    for (int k = 0; k < 4; ++k) {
      int h = ht * 16 + hb * 4 + k;
      bool ok = h < NH;
      x_g[k]     = ok ? g[h] : 0.f;
      x_g[4 + k] = ok ? g[512 + h] : 0.f;
      x_g[8 + k] = ok ? g[1024 + h] : 0.f;
      x_b[k]     = ok ? b_hh[h] : 0.f;
      x_b[4 + k] = ok ? b_hh[NH + h] : 0.f;
      x_b[8 + k] = ok ? b_hh[2 * NH + h] : 0.f;
    }
  }
  f32x4 a0 = {0.f,0.f,0.f,0.f}, a1 = a0, a2 = a0, a3 = a0;
#pragma unroll
  for (int ks = 0; ks < 6; ++ks) {
    a0 = mfma_bf(ag[ks], bg[ks], a0); a1 = mfma_bf(ag[ks], bh[ks], a1);
    a2 = mfma_bf(am[ks], bg[ks], a2); a3 = mfma_bf(am[ks], bh[ks], a3);
  }
  red[(w * 4 + 0) * 64 + l] = a0;
  red[(w * 4 + 1) * 64 + l] = a1;
  red[(w * 4 + 2) * 64 + l] = a2;
  red[(w * 4 + 3) * 64 + l] = a3;
  __syncthreads();
  if (w < 2) {
    int ns = w;
    f32x4 G = red[(0 * 4 + ns) * 64 + l];
    f32x4 M = red[(0 * 4 + 2 + ns) * 64 + l];
#pragma unroll
    for (int p = 1; p < 8; ++p) {
      G += red[(p * 4 + ns) * 64 + l];
      M += red[(p * 4 + 2 + ns) * 64 + l];
    }
    float vout[4];
#pragma unroll
    for (int reg = 0; reg < 4; ++reg) {
      int h = eh0 + reg; float v = 0.f;
      if (h < NH) {
        PcO[h * NB + ec] = G[reg];
        QcO[h * NB + ec] = M[reg];
        float kbv = sigf(e_gb[reg]) * e_mb[reg];
        float fj = sigf(e_dj * G[reg] + e_gb[reg]) * (e_dj * M[reg] + e_mb[reg]);
        RS[h * NB + ec] = fj;
        v = fj + 7.0f * kbv;   // fi = kb, cnt = 6  ->  fj + kb + 6*kb
      }
      vout[reg] = v;
    }
    storeTrio(hinT, ec, eh0, vout);
  } else if (w < 4) {
    int t2 = t - 128;
    int xc = ct * 32 + (t2 & 31);
    int hb = t2 >> 5;
#pragma unroll
    for (int k = 0; k < 4; ++k) {
      int h = ht * 16 + hb * 4 + k;
      if (h < NH) {
        float rr = sigf(x_g[k] + x_b[k]);
        float zz = sigf(x_g[4 + k] + x_b[4 + k]);
        float nn = tanh2(x_g[8 + k] + rr * x_b[8 + k]);
        Xe0[(size_t)xc * KE + h] = (_Float16)((1.f - zz) * nn);
      }
    }
  }
}

// kGM0: mid-inner-step gate/map GEMM; epilogue: RS += fj(cached Pc/Qc), hin trio.
__global__ __launch_bounds__(512) void kGM0(
    const u16* __restrict__ Wgm, const u16* __restrict__ Bsrc,
    const float* __restrict__ dep, const float* __restrict__ gate_b,
    const float* __restrict__ map_b,
    const float* __restrict__ Pcj, const float* __restrict__ Qcj,
    float* __restrict__ RS, u16* __restrict__ hinT, int index, int j) {
  __shared__ f32x4 red[8 * 4 * 64];
  const int b = blockIdx.x, t = threadIdx.x, w = t >> 6, l = t & 63;
  const int quad = l >> 4, lan = l & 15;
  const int ht = b & 31, ct = b >> 5;
  const u16* Ag = Wgm + (size_t)(ht * 16 + lan) * KP;
  const u16* Am = Wgm + (size_t)(512 + ht * 16 + lan) * KP;
  const u16* B0 = Bsrc + (size_t)(ct * 32 + lan) * KP;
  const u16* B1 = Bsrc + (size_t)(ct * 32 + 16 + lan) * KP;
  const int kb = w * 192 + quad * 8;
  bf16x8v bg[6], bh[6], ag[6], am[6];
#pragma unroll
  for (int ks = 0; ks < 6; ++ks) {
    int k = kb + ks * 32;
    int kB = (k < 1024) ? k : k - 1024;
    int kA = (k < 512) ? k : k - 512;
    bg[ks] = *(const bf16x8v*)&B0[kB];
    bh[ks] = *(const bf16x8v*)&B1[kB];
    ag[ks] = *(const bf16x8v*)&Ag[kA];
    am[ks] = *(const bf16x8v*)&Am[kA];
  }
  // epilogue operand hoist
  const int ec = ct * 32 + (w & 1) * 16 + lan;
  const int eh0 = ht * 16 + quad * 4;
  float e_dj = 0.f, e_di = 0.f, e_gb[4], e_mb[4], e_P[4], e_Q[4], e_R[4];
  if (w < 2) {
    e_dj = dep[ec * 64 + index * 8 + j];
    e_di = dep[ec * 64 + index * 8 + index];
#pragma unroll
    for (int r = 0; r < 4; ++r) {
      int h = eh0 + r;
      bool ok = h < NH;
      e_gb[r] = ok ? gate_b[h] : 0.f;
      e_mb[r] = ok ? map_b[h] : 0.f;
      e_P[r]  = ok ? Pcj[h * NB + ec] : 0.f;
      e_Q[r]  = ok ? Qcj[h * NB + ec] : 0.f;
      e_R[r]  = ok ? RS[h * NB + ec] : 0.f;
    }
  }
  f32x4 a0 = {0.f,0.f,0.f,0.f}, a1 = a0, a2 = a0, a3 = a0;
#pragma unroll
  for (int ks = 0; ks < 6; ++ks) {
    a0 = mfma_bf(ag[ks], bg[ks], a0); a1 = mfma_bf(ag[ks], bh[ks], a1);
    a2 = mfma_bf(am[ks], bg[ks], a2); a3 = mfma_bf(am[ks], bh[ks], a3);
  }
  red[(w * 4 + 0) * 64 + l] = a0;
  red[(w * 4 + 1) * 64 + l] = a1;
  red[(w * 4 + 2) * 64 + l] = a2;
  red[(w * 4 + 3) * 64 + l] = a3;
  __syncthreads();
  if (w < 2) {
    int ns = w;
    f32x4 G = red[(0 * 4 + ns) * 64 + l];
    f32x4 M = red[(0 * 4 + 2 + ns) * 64 + l];
#pragma unroll
    for (int p = 1; p < 8; ++p) {
      G += red[(p * 4 + ns) * 64 + l];
      M += red[(p * 4 + 2 + ns) * 64 + l];
    }
    float cnt = (float)(7 - (index - j));
    float vout[4];
#pragma unroll
    for (int reg = 0; reg < 4; ++reg) {
      int h = eh0 + reg; float v = 0.f;
      if (h < NH) {
        float kbv = sigf(e_gb[reg]) * e_mb[reg];
        float fj = sigf(e_dj * e_P[reg] + e_gb[reg]) * (e_dj * e_Q[reg] + e_mb[reg]);
        float rs = e_R[reg] + fj;
        RS[h * NB + ec] = rs;
        float fi = sigf(e_di * G[reg] + e_gb[reg]) * (e_di * M[reg] + e_mb[reg]);
        v = rs + fi + cnt * kbv;
      }
      vout[reg] = v;
    }
    storeTrio(hinT, ec, eh0, vout);
  }
}

// kHHw: gru_hh GEMM + GRU combine. hid from hidF (fp32) or reconstructed from B trio.
__global__ __launch_bounds__(512) void kHHw(
    const u16* __restrict__ Whh, const u16* __restrict__ Bsrc,
    const float* __restrict__ hidF, const float* __restrict__ gi,
    const float* __restrict__ b_hh,
    u16* __restrict__ dstT, _Float16* __restrict__ XeSlot, _Float16* __restrict__ XnSlot) {
  __shared__ f32x4 red[8 * 6 * 64];
  const int b = blockIdx.x, t = threadIdx.x, w = t >> 6, l = t & 63;
  const int quad = l >> 4, lan = l & 15;
  const int ht = b & 31, ct = b >> 5;
  const u16* Ar = Whh + (size_t)(ht * 16 + lan) * KP;
  const u16* Az = Whh + (size_t)(512 + ht * 16 + lan) * KP;
  const u16* An = Whh + (size_t)(1024 + ht * 16 + lan) * KP;
  const u16* B0 = Bsrc + (size_t)(ct * 32 + lan) * KP;
  const u16* B1 = Bsrc + (size_t)(ct * 32 + 16 + lan) * KP;
  const int kb = w * 192 + quad * 8;
  bf16x8v bg[6], bh[6], ar[6], az[6], an[6];
#pragma unroll
  for (int ks = 0; ks < 6; ++ks) {
    int k = kb + ks * 32;
    int kB = (k < 1024) ? k : k - 1024;
    int kA = (k < 512) ? k : k - 512;
    bg[ks] = *(const bf16x8v*)&B0[kB];
    bh[ks] = *(const bf16x8v*)&B1[kB];
    ar[ks] = *(const bf16x8v*)&Ar[kA];
    az[ks] = *(const bf16x8v*)&Az[kA];
    an[ks] = *(const bf16x8v*)&An[kA];
  }
  // epilogue operand hoist
  const int ec = ct * 32 + (w & 1) * 16 + lan;
  const int eh0 = ht * 16 + quad * 4;
  float e_ir[4], e_iz[4], e_inn[4], e_br[4], e_bz[4], e_bn[4], e_hd[4];
  if (w < 2) {
#pragma unroll
    for (int r = 0; r < 4; ++r) {
      int h = eh0 + r;
      bool ok = h < NH;
      e_ir[r]  = ok ? gi[h * NB + ec] : 0.f;
      e_iz[r]  = ok ? gi[(NH + h) * NB + ec] : 0.f;
      e_inn[r] = ok ? gi[(2 * NH + h) * NB + ec] : 0.f;
      e_br[r]  = ok ? b_hh[h] : 0.f;
      e_bz[r]  = ok ? b_hh[NH + h] : 0.f;
      e_bn[r]  = ok ? b_hh[2 * NH + h] : 0.f;
      if (ok) {
        if (hidF) e_hd[r] = hidF[h * NB + ec];
        else e_hd[r] = bf2f(Bsrc[(size_t)ec * KP + h]) + bf2f(Bsrc[(size_t)ec * KP + 512 + h]);
      } else e_hd[r] = 0.f;
    }
  }
  f32x4 r0 = {0.f,0.f,0.f,0.f}, r1 = r0, z0 = r0, z1 = r0, n0 = r0, n1 = r0;
#pragma unroll
  for (int ks = 0; ks < 6; ++ks) {
    r0 = mfma_bf(ar[ks], bg[ks], r0); r1 = mfma_bf(ar[ks], bh[ks], r1);
    z0 = mfma_bf(az[ks], bg[ks], z0); z1 = mfma_bf(az[ks], bh[ks], z1);
    n0 = mfma_bf(an[ks], bg[ks], n0); n1 = mfma_bf(an[ks], bh[ks], n1);
  }
  red[(w * 6 + 0) * 64 + l] = r0;
  red[(w * 6 + 1) * 64 + l] = r1;
  red[(w * 6 + 2) * 64 + l] = z0;
  red[(w * 6 + 3) * 64 + l] = z1;
  red[(w * 6 + 4) * 64 + l] = n0;
  red[(w * 6 + 5) * 64 + l] = n1;
  __syncthreads();
  if (w < 2) {
    int ns = w;
    f32x4 Rr = red[(0 * 6 + 0 + ns) * 64 + l];
    f32x4 Rz = red[(0 * 6 + 2 + ns) * 64 + l];
    f32x4 Rn = red[(0 * 6 + 4 + ns) * 64 + l];
#pragma unroll
    for (int p = 1; p < 8; ++p) {
      Rr += red[(p * 6 + 0 + ns) * 64 + l];
      Rz += red[(p * 6 + 2 + ns) * 64 + l];
      Rn += red[(p * 6 + 4 + ns) * 64 + l];
    }
    float vout[4];
#pragma unroll
    for (int reg = 0; reg < 4; ++reg) {
      int h = eh0 + reg; float v = 0.f;
      if (h < NH) {
        float rr = sigf(e_ir[reg] + Rr[reg] + e_br[reg]);
        float zz = sigf(e_iz[reg] + Rz[reg] + e_bz[reg]);
        float nn = tanh2(e_inn[reg] + rr * (Rn[reg] + e_bn[reg]));
        v = (1.f - zz) * nn + zz * e_hd[reg];
      }
      vout[reg] = v;
    }
    storeTrio(dstT, ec, eh0, vout);
    if (XeSlot || XnSlot) {
      if (eh0 + 3 < NH) {
        f16x4v xv; xv[0] = (_Float16)vout[0]; xv[1] = (_Float16)vout[1];
        xv[2] = (_Float16)vout[2]; xv[3] = (_Float16)vout[3];
        if (XeSlot) *(f16x4v*)&XeSlot[(size_t)ec * KE + eh0] = xv;
        if (XnSlot) *(f16x4v*)&XnSlot[(size_t)ec * KE + eh0] = xv;
      } else {
        for (int reg = 0; reg < 4; ++reg)
          if (eh0 + reg < NH) {
            if (XeSlot) XeSlot[(size_t)ec * KE + eh0 + reg] = (_Float16)vout[reg];
            if (XnSlot) XnSlot[(size_t)ec * KE + eh0 + reg] = (_Float16)vout[reg];
          }
      }
    }
  }
}

// ---------------- deferred ----------------

// kEdge: [Wl|Wr] @ [Xe_s ; Xn_j]  (K=1024 fp16) -> relu(+b1) . ae_w2 -> atomicAdd out0
// Barrier-free: each warp loads its own A/B fragments global->VGPR (L2-resident
// operands), full 32-chunk unroll for load/MFMA overlap. 2x2 warp tiling kept.
// Effective per-lane K segment is quad*8 — identical to the old LDS double-swizzle.
__global__ __launch_bounds__(256) void kEdge(const _Float16* __restrict__ Wlr,
                                             const _Float16* __restrict__ Xe,
                                             const _Float16* __restrict__ Xn,
                                             const float* __restrict__ ae_b1,
                                             const float* __restrict__ ae_w2,
                                             float* __restrict__ out0) {
  __shared__ float shW[4][4][16];
  const int t = threadIdx.x, w = t >> 6, l = t & 63, quad = l >> 4, lan = l & 15;
  const int wm = w >> 1, wn = w & 1;
  const int mB = blockIdx.x * 128, nB0 = blockIdx.y * 128;
  int sid = blockIdx.y >> 1;
  int idec = 1, bse = 0;
  while (sid >= bse + idec) { bse += idec; idec++; }
  int jdec = idec - 1 - (sid - bse);
  // per-fragment row pointers
  const _Float16* Ap[4];
  const _Float16* BpE[4];
  const _Float16* BpN[4];
#pragma unroll
  for (int mt = 0; mt < 4; ++mt)
    Ap[mt] = Wlr + (size_t)(mB + wm * 64 + mt * 16 + lan) * KA + quad * 8;
#pragma unroll
  for (int ns = 0; ns < 4; ++ns) {
    int n = nB0 + wn * 64 + ns * 16 + lan;
    BpE[ns] = Xe + (size_t)n * KE + quad * 8;
    BpN[ns] = Xn + ((size_t)jdec * NB + (n & 255)) * KE + quad * 8;
  }
  // epilogue operand hoist (misses overlap the first chunks)
  float b1v[4][4], w2v[4][4];
#pragma unroll
  for (int mt = 0; mt < 4; ++mt) {
    int m0 = mB + wm * 64 + mt * 16 + quad * 4;
#pragma unroll
    for (int reg = 0; reg < 4; ++reg) {
      int m = m0 + reg;
      b1v[mt][reg] = (m < NH4) ? ae_b1[m] : 0.f;
      w2v[mt][reg] = (m < NH4) ? ae_w2[m] : 0.f;
    }
  }
  f32x4 acc[4][4];
#pragma unroll
  for (int mt = 0; mt < 4; ++mt)
#pragma unroll
    for (int ns = 0; ns < 4; ++ns) acc[mt][ns] = (f32x4){0.f,0.f,0.f,0.f};
#pragma unroll
  for (int c = 0; c < 32; ++c) {
    f16x8v av[4], bv[4];
#pragma unroll
    for (int mt = 0; mt < 4; ++mt) av[mt] = *(const f16x8v*)&Ap[mt][c * 32];
#pragma unroll
    for (int ns = 0; ns < 4; ++ns)
      bv[ns] = (c < 16) ? *(const f16x8v*)&BpE[ns][c * 32]
                        : *(const f16x8v*)&BpN[ns][(c - 16) * 32];
#pragma unroll
    for (int ns = 0; ns < 4; ++ns)
#pragma unroll
      for (int mt = 0; mt < 4; ++mt) acc[mt][ns] = mfma_h(av[mt], bv[ns], acc[mt][ns]);
  }
#pragma unroll
  for (int ns = 0; ns < 4; ++ns) {
    float s = 0.f;
#pragma unroll
    for (int mt = 0; mt < 4; ++mt) {
#pragma unroll
      for (int reg = 0; reg < 4; ++reg) {
        float v = acc[mt][ns][reg] + b1v[mt][reg];
        if (v > 0.f) s += v * w2v[mt][reg];
      }
    }
    s += __shfl_xor(s, 16);
    s += __shfl_xor(s, 32);
    if (quad == 0) shW[w][ns][lan] = s;
  }
  __syncthreads();
  if (t < 128) {
    int ns4 = t >> 4, ln = t & 15;         // col = ns4*16 + ln in [0,128)
    int wn2 = ns4 >> 2, nsl = ns4 & 3;     // contributing warps: wn2 (wm=0), wn2+2 (wm=1)
    float tot = shW[wn2][nsl][ln] + shW[wn2 + 2][nsl][ln];
    int b = (nB0 + ln + ns4 * 16) & 255;
    atomicAdd(&out0[b * 64 + idec * 8 + jdec], tot);
  }
}

// kLogA: t1 = relu(av_w1 @ GS + b1); 64x128 tiles -> grid(16,16) = 256 blocks
// logical K=1536 streamed as 48 chunks of 32; chunk offsets remapped into 2-seg layout.
__global__ __launch_bounds__(256) void kLogA(const u16* __restrict__ Wav1,
                                             const u16* __restrict__ Bsrc,
                                             const float* __restrict__ av_b1,
                                             _Float16* __restrict__ t1) {
  __shared__ u16 sA[2][64 * 32];
  __shared__ u16 sB[2][128 * 32];
  const int t = threadIdx.x, w = t >> 6, l = t & 63, quad = l >> 4, lan = l & 15;
  const int mB = blockIdx.x * 64, nB0 = blockIdx.y * 128;
  const int qs = quad ^ ((lan >> 1) & 3);
  const int sseg = (l & 3) ^ ((l >> 3) & 3);
  int rA = w * 16 + (l >> 2);
  int r0 = (w * 2 + 0) * 16 + (l >> 2), r1 = (w * 2 + 1) * 16 + (l >> 2);
  const u16* gA = Wav1 + (size_t)(mB + rA) * KP + sseg * 8;
  const u16* gB0 = Bsrc + (size_t)(nB0 + r0) * KP + sseg * 8;
  const u16* gB1 = Bsrc + (size_t)(nB0 + r1) * KP + sseg * 8;
  f32x4 acc[8];
#pragma unroll
  for (int ns = 0; ns < 8; ++ns) acc[ns] = (f32x4){0.f,0.f,0.f,0.f};
  {
    __builtin_amdgcn_global_load_lds(
        (const __attribute__((address_space(1))) unsigned int*)gA,
        (__attribute__((address_space(3))) unsigned int*)&sA[0][w * 512], 16, 0, 0);
    __builtin_amdgcn_global_load_lds(
        (const __attribute__((address_space(1))) unsigned int*)gB0,
        (__attribute__((address_space(3))) unsigned int*)&sB[0][(w * 2 + 0) * 512], 16, 0, 0);
    __builtin_amdgcn_global_load_lds(
        (const __attribute__((address_space(1))) unsigned int*)gB1,
        (__attribute__((address_space(3))) unsigned int*)&sB[0][(w * 2 + 1) * 512], 16, 0, 0);
  }
  for (int c = 0; c < 48; ++c) {
    __syncthreads();
    if (c + 1 < 48) {
      int nb = (c + 1) & 1, cc = c + 1;
      int offA = (cc < 16) ? cc * 32 : cc * 32 - 512;    // weights: (hi,hi,lo)
      int offB = (cc < 32) ? cc * 32 : cc * 32 - 1024;   // B slab:  (hi,lo,hi)
      __builtin_amdgcn_global_load_lds(
          (const __attribute__((address_space(1))) unsigned int*)(gA + offA),
          (__attribute__((address_space(3))) unsigned int*)&sA[nb][w * 512], 16, 0, 0);
      __builtin_amdgcn_global_load_lds(
          (const __attribute__((address_space(1))) unsigned int*)(gB0 + offB),
          (__attribute__((address_space(3))) unsigned int*)&sB[nb][(w * 2 + 0) * 512], 16, 0, 0);
      __builtin_amdgcn_global_load_lds(
          (const __attribute__((address_space(1))) unsigned int*)(gB1 + offB),
          (__attribute__((address_space(3))) unsigned int*)&sB[nb][(w * 2 + 1) * 512], 16, 0, 0);
    }
    const u16* bufA = sA[c & 1];
    const u16* bufB = sB[c & 1];
    bf16x8v av = *(const bf16x8v*)&bufA[(w * 16 + lan) * 32 + qs * 8];
#pragma unroll
    for (int ns = 0; ns < 8; ++ns) {
      bf16x8v bv = *(const bf16x8v*)&bufB[(ns * 16 + lan) * 32 + qs * 8];
      acc[ns] = mfma_bf(av, bv, acc[ns]);
    }
  }
#pragma unroll
  for (int ns = 0; ns < 8; ++ns) {
    int col = nB0 + ns * 16 + lan;
    int m0 = mB + w * 16 + quad * 4;
    f16x4v rv;
#pragma unroll
    for (int reg = 0; reg < 4; ++reg) {
      int m = m0 + reg;
      float v = acc[ns][reg] + ((m < NH2) ? av_b1[m] : 0.f);
      rv[reg] = (_Float16)(v > 0.f ? v : 0.f);
    }
    *(f16x4v*)&t1[(size_t)col * 1024 + m0] = rv;
  }
}

__global__ __launch_bounds__(256) void kSoft(const _Float16* __restrict__ t1,
                                             const float* __restrict__ av_w2,
                                             const float* __restrict__ av_b2,
                                             float* __restrict__ out1) {
  const int t = threadIdx.x, w = t >> 6, l = t & 63;
  int col = blockIdx.x * 4 + w;
  const _Float16* trow = t1 + (size_t)col * 1024;
  float s[8] = {};
  for (int i = 0; i < 16; ++i) {
    int k = i * 64 + l;
    if (k < NH2) {
      float v = (float)trow[k];
#pragma unroll
      for (int c = 0; c < 8; ++c) s[c] += v * av_w2[c * NH2 + k];
    }
  }
#pragma unroll
  for (int c = 0; c < 8; ++c) {
    s[c] += __shfl_xor(s[c], 32);
    s[c] += __shfl_xor(s[c], 16);
    s[c] += __shfl_xor(s[c], 8);
    s[c] += __shfl_xor(s[c], 4);
    s[c] += __shfl_xor(s[c], 2);
    s[c] += __shfl_xor(s[c], 1);
  }
  if (l == 0) {
    float lg[8], mx = -1e30f;
#pragma unroll
    for (int c = 0; c < 8; ++c) { lg[c] = s[c] + av_b2[c]; mx = fmaxf(mx, lg[c]); }
    float den = 0.f;
#pragma unroll
    for (int c = 0; c < 8; ++c) den += __expf(lg[c] - mx);
    int idx = col >> 8, b = col & 255;
#pragma unroll
    for (int c = 0; c < 8; ++c)
      out1[(b * NS + idx) * NC + c] = __expf(lg[c] - mx) / den;
  }
}

// ---------------- host ----------------

extern "C" void kernel_launch(void* const* d_in, const int* in_sizes, int n_in,
                              void* d_out, int out_size, void* d_ws, size_t ws_size,
                              hipStream_t stream) {
  (void)in_sizes; (void)n_in; (void)out_size; (void)ws_size;
  const float* z      = (const float*)d_in[0];
  const float* dep    = (const float*)d_in[1];
  const float* ne     = (const float*)d_in[2];
  const float* lin1_w = (const float*)d_in[3];
  const float* lin1_b = (const float*)d_in[4];
  const float* av_w1  = (const float*)d_in[5];
  const float* av_b1  = (const float*)d_in[6];
  const float* av_w2  = (const float*)d_in[7];
  const float* av_b2  = (const float*)d_in[8];
  const float* ae_w1  = (const float*)d_in[9];
  const float* ae_b1  = (const float*)d_in[10];
  const float* ae_w2  = (const float*)d_in[11];
  const float* ae_b2  = (const float*)d_in[12];
  const float* gate_w = (const float*)d_in[13];
  const float* gate_b = (const float*)d_in[14];
  const float* map_w  = (const float*)d_in[15];
  const float* map_b  = (const float*)d_in[16];
  const float* w_ih   = (const float*)d_in[17];
  const float* w_hh   = (const float*)d_in[18];
  const float* b_ih   = (const float*)d_in[19];
  const float* b_hh   = (const float*)d_in[20];

  float* out0 = (float*)d_out;
  float* out1 = out0 + NB * NS * NS;

  const size_t SLOT = (size_t)NB * KP;   // u16 elems per trio slab (2-seg)
  char* p = (char*)d_ws;
  // trio slabs: 0..7 = GS (graph_state at index i); 8 = hinT; 9,10 = hv scratch
  u16* trio = (u16*)p;            p += 11 * SLOT * 2;
  _Float16* Xe = (_Float16*)p;    p += (size_t)28 * NB * KE * 2;
  _Float16* Xn = (_Float16*)p;    p += (size_t)7 * NB * KE * 2;
  u16* Wgm  = (u16*)p;            p += (size_t)1024 * KP * 2;
  u16* Whh  = (u16*)p;            p += (size_t)1536 * KP * 2;
  u16* Wav1 = (u16*)p;            p += (size_t)1024 * KP * 2;
  _Float16* Wlr = (_Float16*)p;   p += (size_t)2048 * KA * 2;
  _Float16* t1 = (_Float16*)p;    p += (size_t)2048 * 1024 * 2;
  float* Pc   = (float*)p;        p += (size_t)8 * HV * 4;
  float* Qc   = (float*)p;        p += (size_t)8 * HV * 4;
  float* RS   = (float*)p;        p += (size_t)HV * 4;
  float* g0   = (float*)p;        p += (size_t)HV * 4;
  float* giN  = (float*)p;        p += (size_t)8 * NH3 * NB * 4;
  float* giT  = (float*)p;        p += (size_t)8 * NB * KG * 4;

  u16* hinT = trio + 8 * SLOT;

  // init (2 launches)
  kPack<<<5632, 256, 0, stream>>>(gate_w, map_w, w_hh, av_w1, ae_w1, Wgm, Whh, Wav1, Wlr);
  kInit<<<617, 256, 0, stream>>>(out0, ae_b2, trio, Xe, Xn,
                                 z, lin1_w, lin1_b, g0, ne, w_ih, b_ih, giN, giT);

  // index 0: hv = gru(x0, graph_state0); final -> GS1 + Xn0
  kHHw<<<256, 512, 0, stream>>>(Whh, trio, g0, giN, b_hh,
                                trio + 1 * SLOT, nullptr, Xn);

  for (int i = 0; i <= 6; ++i) {
    int index = i + 1;
    int sid0 = index * (index - 1) / 2;
    const float* gi_i = giN + (size_t)index * NH3 * NB;
    // transition: Pc/Qc[i] from GS[i+1]; first-inner-step hin + RS; hv0 -> Xe
    kGMT<<<256, 512, 0, stream>>>(Wgm, trio + (size_t)(i + 1) * SLOT,
                                  Pc + (size_t)i * HV, Qc + (size_t)i * HV,
                                  dep, gate_b, map_b, RS, hinT, giT, b_hh,
                                  Xe + (size_t)sid0 * NB * KE, index);
    // first HH of this outer step (inner j = index-1)
    bool final1 = (index == 1);
    u16* dst = final1 ? (trio + 2 * SLOT) : (trio + 9 * SLOT);
    kHHw<<<256, 512, 0, stream>>>(Whh, hinT, nullptr, gi_i, b_hh, dst,
        (index - 1 > 0) ? (Xe + (size_t)(sid0 + 1) * NB * KE) : nullptr,
        final1 ? (Xn + (size_t)1 * NB * KE) : nullptr);
    u16* prev = dst;
    int par = 1;
    for (int j = index - 2; j >= 0; --j) {
      kGM0<<<256, 512, 0, stream>>>(Wgm, prev, dep, gate_b, map_b,
                                    Pc + (size_t)j * HV, Qc + (size_t)j * HV,
                                    RS, hinT, index, j);
      bool fin = (j == 0);
      u16* d2 = (fin && index <= 6) ? (trio + (size_t)(index + 1) * SLOT)
                                    : (trio + (size_t)(9 + par) * SLOT);
      kHHw<<<256, 512, 0, stream>>>(Whh, hinT, nullptr, gi_i, b_hh, d2,
          (j > 0) ? (Xe + (size_t)(sid0 + index - j) * NB * KE) : nullptr,
          (fin && index <= 6) ? (Xn + (size_t)index * NB * KE) : nullptr);
      prev = d2; par ^= 1;
    }
  }

  // deferred (3 launches)
  kLogA<<<dim3(16, 16), 256, 0, stream>>>(Wav1, trio, av_b1, t1);
  kSoft<<<512, 256, 0, stream>>>(t1, av_w2, av_b2, out1);
  kEdge<<<dim3(16, 56), 256, 0, stream>>>(Wlr, Xe, Xn, ae_b1, ae_w2, out0);
}

// Round 13
// 797.810 us; speedup vs baseline: 1.0995x; 1.0995x over previous
//
#include <hip/hip_runtime.h>
#include <math.h>

constexpr int NB  = 256;
constexpr int NS  = 8;
constexpr int NC  = 8;
constexpr int NH  = 501;
constexpr int NL  = 56;
constexpr int NH2 = 1002;
constexpr int NH3 = 1503;
constexpr int NH4 = 2004;
constexpr int KP  = 1024;   // PHYSICAL trio K: 2 segs (hi|lo). Logical K=1536 via remap:
                            //   weights (hi,hi,lo): kA = k<512 ? k : k-512
                            //   B slabs (hi,lo,hi): kB = k<1024 ? k : k-1024
constexpr int KG  = 1536;   // giT stride (3 distinct gates r,z,n — NOT a trio)
constexpr int KE  = 512;    // fp16 snapshot K
constexpr int KA  = 1024;   // edge GEMM K ([hv ; nhs_j])
constexpr int HV  = 512 * 256;

typedef unsigned short u16;
typedef short bf16x8v __attribute__((ext_vector_type(8)));
typedef _Float16 f16x8v __attribute__((ext_vector_type(8)));
typedef _Float16 f16x4v __attribute__((ext_vector_type(4)));
typedef float f32x4 __attribute__((ext_vector_type(4)));

__device__ __forceinline__ float sigf(float x) { return 1.0f / (1.0f + __expf(-x)); }
__device__ __forceinline__ float tanh2(float x) { return 2.0f * sigf(2.0f * x) - 1.0f; }

__device__ __forceinline__ u16 f2bf(float x) {
  union { float f; unsigned u; } c; c.f = x;
  unsigned r = (c.u + 0x7fffu + ((c.u >> 16) & 1u)) >> 16;
  return (u16)r;
}
__device__ __forceinline__ float bf2f(u16 h) {
  union { float f; unsigned u; } c; c.u = ((unsigned)h) << 16; return c.f;
}

__device__ __forceinline__ void async_copy16(const void* g, void* l) {
  __builtin_amdgcn_global_load_lds(
      (const __attribute__((address_space(1))) unsigned int*)g,
      (__attribute__((address_space(3))) unsigned int*)l, 16, 0, 0);
}

__device__ __forceinline__ f32x4 mfma_bf(bf16x8v a, bf16x8v b, f32x4 c) {
  return __builtin_amdgcn_mfma_f32_16x16x32_bf16(a, b, c, 0, 0, 0);
}
__device__ __forceinline__ f32x4 mfma_h(f16x8v a, f16x8v b, f32x4 c) {
  return __builtin_amdgcn_mfma_f32_16x16x32_f16(a, b, c, 0, 0, 0);
}

// 2-seg trio store: (hi | lo). Logical seg 3 (hi) is read via address remap.
__device__ __forceinline__ void storeTrio(u16* __restrict__ T, int b, int h0, const float v[4]) {
  size_t base = (size_t)b * KP;
  if (h0 + 3 < NH) {
    ushort4 hi4, lo4;
    u16 hi, lo;
    hi = f2bf(v[0]); lo = f2bf(v[0] - bf2f(hi)); hi4.x = hi; lo4.x = lo;
    hi = f2bf(v[1]); lo = f2bf(v[1] - bf2f(hi)); hi4.y = hi; lo4.y = lo;
    hi = f2bf(v[2]); lo = f2bf(v[2] - bf2f(hi)); hi4.z = hi; lo4.z = lo;
    hi = f2bf(v[3]); lo = f2bf(v[3] - bf2f(hi)); hi4.w = hi; lo4.w = lo;
    *(ushort4*)&T[base + h0]       = hi4;
    *(ushort4*)&T[base + 512 + h0] = lo4;
  } else {
    for (int r = 0; r < 4; ++r) {
      int h = h0 + r;
      if (h < NH) {
        u16 hi = f2bf(v[r]); u16 lo = f2bf(v[r] - bf2f(hi));
        T[base + h] = hi; T[base + 512 + h] = lo;
      }
    }
  }
}

// ---------------- pack ----------------
__global__ __launch_bounds__(256) void kPack(
    const float* __restrict__ gate_w, const float* __restrict__ map_w,
    const float* __restrict__ w_hh, const float* __restrict__ av_w1,
    const float* __restrict__ ae_w1,
    u16* __restrict__ Wgm, u16* __restrict__ Whh, u16* __restrict__ Wav1,
    _Float16* __restrict__ Wlr) {
  int r = blockIdx.x;
  if (r < 3584) {
    for (int k = threadIdx.x; k < 512; k += 256) {
      float v = 0.f; u16* dst; int rr;
      if (r < 1024) {
        int h = (r < 512) ? r : r - 512;
        if (h < NH && k < NH) v = (r < 512) ? gate_w[h * NH + k] : map_w[h * NH + k];
        dst = Wgm; rr = r;
      } else if (r < 2560) {
        rr = r - 1024; int g = rr >> 9, h = rr & 511;
        if (h < NH && k < NH) v = w_hh[((size_t)g * NH + h) * NH + k];
        dst = Whh;
      } else {
        rr = r - 2560;
        if (rr < NH2 && k < NH) v = av_w1[(size_t)rr * NH + k];
        dst = Wav1;
      }
      u16 hi = f2bf(v); u16 lo = f2bf(v - bf2f(hi));
      dst[(size_t)rr * KP + k] = hi;
      dst[(size_t)rr * KP + 512 + k] = lo;
    }
  } else {
    int m = r - 3584;
    for (int k = threadIdx.x; k < KA; k += 256) {
      float v = 0.f;
      if (m < NH4) {
        if (k < 512) { if (k < NH) v = ae_w1[(size_t)m * NH2 + k]; }
        else { int kk = k - 512; if (kk < NH) v = ae_w1[(size_t)m * NH2 + NH + kk]; }
      }
      Wlr[(size_t)m * KA + k] = (_Float16)v;
    }
  }
}

// ---------------- merged init ----------------
__global__ __launch_bounds__(256) void kInit(
    float* __restrict__ out0, const float* __restrict__ ae_b2,
    u16* __restrict__ trio, _Float16* __restrict__ Xe, _Float16* __restrict__ Xn,
    const float* __restrict__ z, const float* __restrict__ lin1_w,
    const float* __restrict__ lin1_b, float* __restrict__ g0,
    const float* __restrict__ ne, const float* __restrict__ w_ih,
    const float* __restrict__ b_ih, float* __restrict__ giN, float* __restrict__ giT) {
  int blk = blockIdx.x, t = threadIdx.x;
  if (blk < 64) {
    int e = blk * 256 + t;
    int b = e >> 6, r = e & 63;
    int i = r >> 3, jj = r & 7;
    out0[b * 64 + i * 8 + jj] = (jj < i) ? ae_b2[0] : 0.f;
  } else if (blk < 75) {
    u16* T = trio + (size_t)(blk - 64) * ((size_t)NB * KP) + (size_t)t * KP;
#pragma unroll
    for (int seg = 0; seg < 2; ++seg)
      for (int h = NH; h < 512; ++h) T[seg * 512 + h] = 0;
  } else if (blk < 103) {
    _Float16* X = Xe + (size_t)(blk - 75) * NB * KE + (size_t)t * KE;
    for (int h = NH; h < 512; ++h) X[h] = (_Float16)0.f;
  } else if (blk < 110) {
    _Float16* X = Xn + (size_t)(blk - 103) * NB * KE + (size_t)t * KE;
    for (int h = NH; h < 512; ++h) X[h] = (_Float16)0.f;
  } else if (blk < 366) {
    int b = blk - 110;
    const float* zr = z + (size_t)b * NL;
    for (int h = t; h < NH; h += 256) {
      const float* wr = lin1_w + (size_t)h * NL;
      float acc = lin1_b[h];
#pragma unroll
      for (int l = 0; l < NL; ++l) acc += zr[l] * wr[l];
      g0[h * NB + b] = acc;
      u16 hi = f2bf(acc), lo = f2bf(acc - bf2f(hi));
      trio[(size_t)b * KP + h] = hi;
      trio[(size_t)b * KP + 512 + h] = lo;
    }
  } else {
    int r0 = (blk - 366) * 6, b = t;
    for (int rr = 0; rr < 6; ++rr) {
      int r = r0 + rr;
      if (r >= NH3) break;
      int g = (r >= NH2) ? 2 : ((r >= NH) ? 1 : 0);
      int h = r - g * NH;
      float wv[8];
#pragma unroll
      for (int c = 0; c < 8; ++c) wv[c] = w_ih[r * NC + c];
      float bb = b_ih[r];
      for (int idx = 0; idx < 8; ++idx) {
        float acc = bb;
#pragma unroll
        for (int c = 0; c < 8; ++c) acc += ne[b * 64 + idx * 8 + c] * wv[c];
        giN[((size_t)idx * NH3 + r) * NB + b] = acc;
        giT[((size_t)idx * NB + b) * KG + g * 512 + h] = acc;
      }
    }
  }
}

// ---------------- loop kernels ----------------
// 512 threads / 8 waves; logical K=1536 split 8x192/wave, 2-seg physical layout.
// A+B register-batch-prefetched, epilogue operands hoisted.
// XCD swizzle: ht = (b&7)*4 + ((b>>3)&3), ct = b>>5 — with round-robin
// block->XCD dispatch, each XCD owns a contiguous ht-quarter for ALL ct,
// so weight rows are fetched once per XCD and L2-hit by ct-siblings.

// kGMT: transition i -> i+1.
__global__ __launch_bounds__(512) void kGMT(
    const u16* __restrict__ Wgm, const u16* __restrict__ Bsrc,
    float* __restrict__ PcO, float* __restrict__ QcO,
    const float* __restrict__ dep, const float* __restrict__ gate_b,
    const float* __restrict__ map_b, float* __restrict__ RS, u16* __restrict__ hinT,
    const float* __restrict__ giT, const float* __restrict__ b_hh,
    _Float16* __restrict__ Xe0, int index) {
  __shared__ f32x4 red[8 * 4 * 64];
  const int b = blockIdx.x, t = threadIdx.x, w = t >> 6, l = t & 63;
  const int quad = l >> 4, lan = l & 15;
  const int ht = (b & 7) * 4 + ((b >> 3) & 3), ct = b >> 5;
  const u16* Ag = Wgm + (size_t)(ht * 16 + lan) * KP;
  const u16* Am = Wgm + (size_t)(512 + ht * 16 + lan) * KP;
  const u16* B0 = Bsrc + (size_t)(ct * 32 + lan) * KP;
  const u16* B1 = Bsrc + (size_t)(ct * 32 + 16 + lan) * KP;
  const int kb = w * 192 + quad * 8;
  bf16x8v bg[6], bh[6], ag[6], am[6];
#pragma unroll
  for (int ks = 0; ks < 6; ++ks) {
    int k = kb + ks * 32;
    int kB = (k < 1024) ? k : k - 1024;
    int kA = (k < 512) ? k : k - 512;
    bg[ks] = *(const bf16x8v*)&B0[kB];
    bh[ks] = *(const bf16x8v*)&B1[kB];
    ag[ks] = *(const bf16x8v*)&Ag[kA];
    am[ks] = *(const bf16x8v*)&Am[kA];
  }
  // epilogue operand hoist
  const int ec = ct * 32 + (w & 1) * 16 + lan;   // ns = w for w<2
  const int eh0 = ht * 16 + quad * 4;
  float e_dj = 0.f, e_gb[4], e_mb[4];
  float x_g[12], x_b[12];
  if (w < 2) {
    e_dj = dep[ec * 64 + index * 8 + (index - 1)];
#pragma unroll
    for (int r = 0; r < 4; ++r) {
      int h = eh0 + r;
      bool ok = h < NH;
      e_gb[r] = ok ? gate_b[h] : 0.f;
      e_mb[r] = ok ? map_b[h] : 0.f;
    }
  } else if (w < 4) {
    int t2 = t - 128;
    int xc = ct * 32 + (t2 & 31);
    int hb = t2 >> 5;
    const float* g = giT + ((size_t)index * NB + xc) * KG;
#pragma unroll
    for (int k = 0; k < 4; ++k) {
      int h = ht * 16 + hb * 4 + k;
      bool ok = h < NH;
      x_g[k]     = ok ? g[h] : 0.f;
      x_g[4 + k] = ok ? g[512 + h] : 0.f;
      x_g[8 + k] = ok ? g[1024 + h] : 0.f;
      x_b[k]     = ok ? b_hh[h] : 0.f;
      x_b[4 + k] = ok ? b_hh[NH + h] : 0.f;
      x_b[8 + k] = ok ? b_hh[2 * NH + h] : 0.f;
    }
  }
  f32x4 a0 = {0.f,0.f,0.f,0.f}, a1 = a0, a2 = a0, a3 = a0;
#pragma unroll
  for (int ks = 0; ks < 6; ++ks) {
    a0 = mfma_bf(ag[ks], bg[ks], a0); a1 = mfma_bf(ag[ks], bh[ks], a1);
    a2 = mfma_bf(am[ks], bg[ks], a2); a3 = mfma_bf(am[ks], bh[ks], a3);
  }
  red[(w * 4 + 0) * 64 + l] = a0;
  red[(w * 4 + 1) * 64 + l] = a1;
  red[(w * 4 + 2) * 64 + l] = a2;
  red[(w * 4 + 3) * 64 + l] = a3;
  __syncthreads();
  if (w < 2) {
    int ns = w;
    f32x4 G = red[(0 * 4 + ns) * 64 + l];
    f32x4 M = red[(0 * 4 + 2 + ns) * 64 + l];
#pragma unroll
    for (int p = 1; p < 8; ++p) {
      G += red[(p * 4 + ns) * 64 + l];
      M += red[(p * 4 + 2 + ns) * 64 + l];
    }
    float vout[4];
#pragma unroll
    for (int reg = 0; reg < 4; ++reg) {
      int h = eh0 + reg; float v = 0.f;
      if (h < NH) {
        PcO[h * NB + ec] = G[reg];
        QcO[h * NB + ec] = M[reg];
        float kbv = sigf(e_gb[reg]) * e_mb[reg];
        float fj = sigf(e_dj * G[reg] + e_gb[reg]) * (e_dj * M[reg] + e_mb[reg]);
        RS[h * NB + ec] = fj;
        v = fj + 7.0f * kbv;   // fi = kb, cnt = 6  ->  fj + kb + 6*kb
      }
      vout[reg] = v;
    }
    storeTrio(hinT, ec, eh0, vout);
  } else if (w < 4) {
    int t2 = t - 128;
    int xc = ct * 32 + (t2 & 31);
    int hb = t2 >> 5;
#pragma unroll
    for (int k = 0; k < 4; ++k) {
      int h = ht * 16 + hb * 4 + k;
      if (h < NH) {
        float rr = sigf(x_g[k] + x_b[k]);
        float zz = sigf(x_g[4 + k] + x_b[4 + k]);
        float nn = tanh2(x_g[8 + k] + rr * x_b[8 + k]);
        Xe0[(size_t)xc * KE + h] = (_Float16)((1.f - zz) * nn);
      }
    }
  }
}

// kGM0: mid-inner-step gate/map GEMM; epilogue: RS += fj(cached Pc/Qc), hin trio.
__global__ __launch_bounds__(512) void kGM0(
    const u16* __restrict__ Wgm, const u16* __restrict__ Bsrc,
    const float* __restrict__ dep, const float* __restrict__ gate_b,
    const float* __restrict__ map_b,
    const float* __restrict__ Pcj, const float* __restrict__ Qcj,
    float* __restrict__ RS, u16* __restrict__ hinT, int index, int j) {
  __shared__ f32x4 red[8 * 4 * 64];
  const int b = blockIdx.x, t = threadIdx.x, w = t >> 6, l = t & 63;
  const int quad = l >> 4, lan = l & 15;
  const int ht = (b & 7) * 4 + ((b >> 3) & 3), ct = b >> 5;
  const u16* Ag = Wgm + (size_t)(ht * 16 + lan) * KP;
  const u16* Am = Wgm + (size_t)(512 + ht * 16 + lan) * KP;
  const u16* B0 = Bsrc + (size_t)(ct * 32 + lan) * KP;
  const u16* B1 = Bsrc + (size_t)(ct * 32 + 16 + lan) * KP;
  const int kb = w * 192 + quad * 8;
  bf16x8v bg[6], bh[6], ag[6], am[6];
#pragma unroll
  for (int ks = 0; ks < 6; ++ks) {
    int k = kb + ks * 32;
    int kB = (k < 1024) ? k : k - 1024;
    int kA = (k < 512) ? k : k - 512;
    bg[ks] = *(const bf16x8v*)&B0[kB];
    bh[ks] = *(const bf16x8v*)&B1[kB];
    ag[ks] = *(const bf16x8v*)&Ag[kA];
    am[ks] = *(const bf16x8v*)&Am[kA];
  }
  // epilogue operand hoist
  const int ec = ct * 32 + (w & 1) * 16 + lan;
  const int eh0 = ht * 16 + quad * 4;
  float e_dj = 0.f, e_di = 0.f, e_gb[4], e_mb[4], e_P[4], e_Q[4], e_R[4];
  if (w < 2) {
    e_dj = dep[ec * 64 + index * 8 + j];
    e_di = dep[ec * 64 + index * 8 + index];
#pragma unroll
    for (int r = 0; r < 4; ++r) {
      int h = eh0 + r;
      bool ok = h < NH;
      e_gb[r] = ok ? gate_b[h] : 0.f;
      e_mb[r] = ok ? map_b[h] : 0.f;
      e_P[r]  = ok ? Pcj[h * NB + ec] : 0.f;
      e_Q[r]  = ok ? Qcj[h * NB + ec] : 0.f;
      e_R[r]  = ok ? RS[h * NB + ec] : 0.f;
    }
  }
  f32x4 a0 = {0.f,0.f,0.f,0.f}, a1 = a0, a2 = a0, a3 = a0;
#pragma unroll
  for (int ks = 0; ks < 6; ++ks) {
    a0 = mfma_bf(ag[ks], bg[ks], a0); a1 = mfma_bf(ag[ks], bh[ks], a1);
    a2 = mfma_bf(am[ks], bg[ks], a2); a3 = mfma_bf(am[ks], bh[ks], a3);
  }
  red[(w * 4 + 0) * 64 + l] = a0;
  red[(w * 4 + 1) * 64 + l] = a1;
  red[(w * 4 + 2) * 64 + l] = a2;
  red[(w * 4 + 3) * 64 + l] = a3;
  __syncthreads();
  if (w < 2) {
    int ns = w;
    f32x4 G = red[(0 * 4 + ns) * 64 + l];
    f32x4 M = red[(0 * 4 + 2 + ns) * 64 + l];
#pragma unroll
    for (int p = 1; p < 8; ++p) {
      G += red[(p * 4 + ns) * 64 + l];
      M += red[(p * 4 + 2 + ns) * 64 + l];
    }
    float cnt = (float)(7 - (index - j));
    float vout[4];
#pragma unroll
    for (int reg = 0; reg < 4; ++reg) {
      int h = eh0 + reg; float v = 0.f;
      if (h < NH) {
        float kbv = sigf(e_gb[reg]) * e_mb[reg];
        float fj = sigf(e_dj * e_P[reg] + e_gb[reg]) * (e_dj * e_Q[reg] + e_mb[reg]);
        float rs = e_R[reg] + fj;
        RS[h * NB + ec] = rs;
        float fi = sigf(e_di * G[reg] + e_gb[reg]) * (e_di * M[reg] + e_mb[reg]);
        v = rs + fi + cnt * kbv;
      }
      vout[reg] = v;
    }
    storeTrio(hinT, ec, eh0, vout);
  }
}

// kHHw: gru_hh GEMM + GRU combine. hid from hidF (fp32) or reconstructed from B trio.
__global__ __launch_bounds__(512) void kHHw(
    const u16* __restrict__ Whh, const u16* __restrict__ Bsrc,
    const float* __restrict__ hidF, const float* __restrict__ gi,
    const float* __restrict__ b_hh,
    u16* __restrict__ dstT, _Float16* __restrict__ XeSlot, _Float16* __restrict__ XnSlot) {
  __shared__ f32x4 red[8 * 6 * 64];
  const int b = blockIdx.x, t = threadIdx.x, w = t >> 6, l = t & 63;
  const int quad = l >> 4, lan = l & 15;
  const int ht = (b & 7) * 4 + ((b >> 3) & 3), ct = b >> 5;
  const u16* Ar = Whh + (size_t)(ht * 16 + lan) * KP;
  const u16* Az = Whh + (size_t)(512 + ht * 16 + lan) * KP;
  const u16* An = Whh + (size_t)(1024 + ht * 16 + lan) * KP;
  const u16* B0 = Bsrc + (size_t)(ct * 32 + lan) * KP;
  const u16* B1 = Bsrc + (size_t)(ct * 32 + 16 + lan) * KP;
  const int kb = w * 192 + quad * 8;
  bf16x8v bg[6], bh[6], ar[6], az[6], an[6];
#pragma unroll
  for (int ks = 0; ks < 6; ++ks) {
    int k = kb + ks * 32;
    int kB = (k < 1024) ? k : k - 1024;
    int kA = (k < 512) ? k : k - 512;
    bg[ks] = *(const bf16x8v*)&B0[kB];
    bh[ks] = *(const bf16x8v*)&B1[kB];
    ar[ks] = *(const bf16x8v*)&Ar[kA];
    az[ks] = *(const bf16x8v*)&Az[kA];
    an[ks] = *(const bf16x8v*)&An[kA];
  }
  // epilogue operand hoist
  const int ec = ct * 32 + (w & 1) * 16 + lan;
  const int eh0 = ht * 16 + quad * 4;
  float e_ir[4], e_iz[4], e_inn[4], e_br[4], e_bz[4], e_bn[4], e_hd[4];
  if (w < 2) {
#pragma unroll
    for (int r = 0; r < 4; ++r) {
      int h = eh0 + r;
      bool ok = h < NH;
      e_ir[r]  = ok ? gi[h * NB + ec] : 0.f;
      e_iz[r]  = ok ? gi[(NH + h) * NB + ec] : 0.f;
      e_inn[r] = ok ? gi[(2 * NH + h) * NB + ec] : 0.f;
      e_br[r]  = ok ? b_hh[h] : 0.f;
      e_bz[r]  = ok ? b_hh[NH + h] : 0.f;
      e_bn[r]  = ok ? b_hh[2 * NH + h] : 0.f;
      if (ok) {
        if (hidF) e_hd[r] = hidF[h * NB + ec];
        else e_hd[r] = bf2f(Bsrc[(size_t)ec * KP + h]) + bf2f(Bsrc[(size_t)ec * KP + 512 + h]);
      } else e_hd[r] = 0.f;
    }
  }
  f32x4 r0 = {0.f,0.f,0.f,0.f}, r1 = r0, z0 = r0, z1 = r0, n0 = r0, n1 = r0;
#pragma unroll
  for (int ks = 0; ks < 6; ++ks) {
    r0 = mfma_bf(ar[ks], bg[ks], r0); r1 = mfma_bf(ar[ks], bh[ks], r1);
    z0 = mfma_bf(az[ks], bg[ks], z0); z1 = mfma_bf(az[ks], bh[ks], z1);
    n0 = mfma_bf(an[ks], bg[ks], n0); n1 = mfma_bf(an[ks], bh[ks], n1);
  }
  red[(w * 6 + 0) * 64 + l] = r0;
  red[(w * 6 + 1) * 64 + l] = r1;
  red[(w * 6 + 2) * 64 + l] = z0;
  red[(w * 6 + 3) * 64 + l] = z1;
  red[(w * 6 + 4) * 64 + l] = n0;
  red[(w * 6 + 5) * 64 + l] = n1;
  __syncthreads();
  if (w < 2) {
    int ns = w;
    f32x4 Rr = red[(0 * 6 + 0 + ns) * 64 + l];
    f32x4 Rz = red[(0 * 6 + 2 + ns) * 64 + l];
    f32x4 Rn = red[(0 * 6 + 4 + ns) * 64 + l];
#pragma unroll
    for (int p = 1; p < 8; ++p) {
      Rr += red[(p * 6 + 0 + ns) * 64 + l];
      Rz += red[(p * 6 + 2 + ns) * 64 + l];
      Rn += red[(p * 6 + 4 + ns) * 64 + l];
    }
    float vout[4];
#pragma unroll
    for (int reg = 0; reg < 4; ++reg) {
      int h = eh0 + reg; float v = 0.f;
      if (h < NH) {
        float rr = sigf(e_ir[reg] + Rr[reg] + e_br[reg]);
        float zz = sigf(e_iz[reg] + Rz[reg] + e_bz[reg]);
        float nn = tanh2(e_inn[reg] + rr * (Rn[reg] + e_bn[reg]));
        v = (1.f - zz) * nn + zz * e_hd[reg];
      }
      vout[reg] = v;
    }
    storeTrio(dstT, ec, eh0, vout);
    if (XeSlot || XnSlot) {
      if (eh0 + 3 < NH) {
        f16x4v xv; xv[0] = (_Float16)vout[0]; xv[1] = (_Float16)vout[1];
        xv[2] = (_Float16)vout[2]; xv[3] = (_Float16)vout[3];
        if (XeSlot) *(f16x4v*)&XeSlot[(size_t)ec * KE + eh0] = xv;
        if (XnSlot) *(f16x4v*)&XnSlot[(size_t)ec * KE + eh0] = xv;
      } else {
        for (int reg = 0; reg < 4; ++reg)
          if (eh0 + reg < NH) {
            if (XeSlot) XeSlot[(size_t)ec * KE + eh0 + reg] = (_Float16)vout[reg];
            if (XnSlot) XnSlot[(size_t)ec * KE + eh0 + reg] = (_Float16)vout[reg];
          }
      }
    }
  }
}

// ---------------- deferred ----------------

// kEdge: [Wl|Wr] @ [Xe_s ; Xn_j]  (K=1024 fp16) -> relu(+b1) . ae_w2 -> atomicAdd out0
// LDS-staged (coalesced async copies) + 2x2 warp tiling (best measured: 56.9 us).
__global__ __launch_bounds__(256) void kEdge(const _Float16* __restrict__ Wlr,
                                             const _Float16* __restrict__ Xe,
                                             const _Float16* __restrict__ Xn,
                                             const float* __restrict__ ae_b1,
                                             const float* __restrict__ ae_w2,
                                             float* __restrict__ out0) {
  __shared__ u16 sA[2][128 * 32];
  __shared__ u16 sB[2][128 * 32];
  __shared__ float shW[4][4][16];
  const int t = threadIdx.x, w = t >> 6, l = t & 63, quad = l >> 4, lan = l & 15;
  const int wm = w >> 1, wn = w & 1;
  const int mB = blockIdx.x * 128, nB0 = blockIdx.y * 128;
  const int qs = quad ^ ((lan >> 1) & 3);
  const int sseg = (l & 3) ^ ((l >> 3) & 3);
  int sid = blockIdx.y >> 1;
  int idec = 1, bse = 0;
  while (sid >= bse + idec) { bse += idec; idec++; }
  int jdec = idec - 1 - (sid - bse);
  int r0 = (w * 2 + 0) * 16 + (l >> 2), r1 = (w * 2 + 1) * 16 + (l >> 2);
  const _Float16* gA0 = Wlr + (size_t)(mB + r0) * KA + sseg * 8;
  const _Float16* gA1 = Wlr + (size_t)(mB + r1) * KA + sseg * 8;
  const _Float16* Xe0 = Xe + (size_t)(nB0 + r0) * KE + sseg * 8;
  const _Float16* Xe1 = Xe + (size_t)(nB0 + r1) * KE + sseg * 8;
  const _Float16* Xn0 = Xn + ((size_t)jdec * NB + ((nB0 + r0) & 255)) * KE + sseg * 8;
  const _Float16* Xn1 = Xn + ((size_t)jdec * NB + ((nB0 + r1) & 255)) * KE + sseg * 8;
  // epilogue operand hoist (overlaps with first chunks)
  float b1v[4][4], w2v[4][4];
#pragma unroll
  for (int mt = 0; mt < 4; ++mt) {
    int m0 = mB + wm * 64 + mt * 16 + quad * 4;
#pragma unroll
    for (int reg = 0; reg < 4; ++reg) {
      int m = m0 + reg;
      b1v[mt][reg] = (m < NH4) ? ae_b1[m] : 0.f;
      w2v[mt][reg] = (m < NH4) ? ae_w2[m] : 0.f;
    }
  }
  f32x4 acc[4][4];
#pragma unroll
  for (int mt = 0; mt < 4; ++mt)
#pragma unroll
    for (int ns = 0; ns < 4; ++ns) acc[mt][ns] = (f32x4){0.f,0.f,0.f,0.f};
  async_copy16(gA0, &sA[0][(w * 2 + 0) * 512]);
  async_copy16(gA1, &sA[0][(w * 2 + 1) * 512]);
  async_copy16(Xe0, &sB[0][(w * 2 + 0) * 512]);
  async_copy16(Xe1, &sB[0][(w * 2 + 1) * 512]);
  for (int c = 0; c < 32; ++c) {
    __syncthreads();
    if (c + 1 < 32) {
      int nb = (c + 1) & 1, cc = c + 1;
      async_copy16(gA0 + cc * 32, &sA[nb][(w * 2 + 0) * 512]);
      async_copy16(gA1 + cc * 32, &sA[nb][(w * 2 + 1) * 512]);
      const _Float16* b0 = (cc < 16) ? (Xe0 + cc * 32) : (Xn0 + (cc - 16) * 32);
      const _Float16* b1 = (cc < 16) ? (Xe1 + cc * 32) : (Xn1 + (cc - 16) * 32);
      async_copy16(b0, &sB[nb][(w * 2 + 0) * 512]);
      async_copy16(b1, &sB[nb][(w * 2 + 1) * 512]);
    }
    const u16* bufA = sA[c & 1];
    const u16* bufB = sB[c & 1];
    f16x8v av[4];
#pragma unroll
    for (int mt = 0; mt < 4; ++mt)
      av[mt] = *(const f16x8v*)&bufA[(wm * 64 + mt * 16 + lan) * 32 + qs * 8];
#pragma unroll
    for (int ns = 0; ns < 4; ++ns) {
      f16x8v bv = *(const f16x8v*)&bufB[(wn * 64 + ns * 16 + lan) * 32 + qs * 8];
#pragma unroll
      for (int mt = 0; mt < 4; ++mt) acc[mt][ns] = mfma_h(av[mt], bv, acc[mt][ns]);
    }
  }
#pragma unroll
  for (int ns = 0; ns < 4; ++ns) {
    float s = 0.f;
#pragma unroll
    for (int mt = 0; mt < 4; ++mt) {
#pragma unroll
      for (int reg = 0; reg < 4; ++reg) {
        float v = acc[mt][ns][reg] + b1v[mt][reg];
        if (v > 0.f) s += v * w2v[mt][reg];
      }
    }
    s += __shfl_xor(s, 16);
    s += __shfl_xor(s, 32);
    if (quad == 0) shW[w][ns][lan] = s;
  }
  __syncthreads();
  if (t < 128) {
    int ns4 = t >> 4, ln = t & 15;         // col = ns4*16 + ln in [0,128)
    int wn2 = ns4 >> 2, nsl = ns4 & 3;     // contributing warps: wn2 (wm=0), wn2+2 (wm=1)
    float tot = shW[wn2][nsl][ln] + shW[wn2 + 2][nsl][ln];
    int b = (nB0 + ln + ns4 * 16) & 255;
    atomicAdd(&out0[b * 64 + idec * 8 + jdec], tot);
  }
}

// kLogA: t1 = relu(av_w1 @ GS + b1); 64x128 tiles -> grid(16,16) = 256 blocks
__global__ __launch_bounds__(256) void kLogA(const u16* __restrict__ Wav1,
                                             const u16* __restrict__ Bsrc,
                                             const float* __restrict__ av_b1,
                                             _Float16* __restrict__ t1) {
  __shared__ u16 sA[2][64 * 32];
  __shared__ u16 sB[2][128 * 32];
  const int t = threadIdx.x, w = t >> 6, l = t & 63, quad = l >> 4, lan = l & 15;
  const int mB = blockIdx.x * 64, nB0 = blockIdx.y * 128;
  const int qs = quad ^ ((lan >> 1) & 3);
  const int sseg = (l & 3) ^ ((l >> 3) & 3);
  int rA = w * 16 + (l >> 2);
  int r0 = (w * 2 + 0) * 16 + (l >> 2), r1 = (w * 2 + 1) * 16 + (l >> 2);
  const u16* gA = Wav1 + (size_t)(mB + rA) * KP + sseg * 8;
  const u16* gB0 = Bsrc + (size_t)(nB0 + r0) * KP + sseg * 8;
  const u16* gB1 = Bsrc + (size_t)(nB0 + r1) * KP + sseg * 8;
  f32x4 acc[8];
#pragma unroll
  for (int ns = 0; ns < 8; ++ns) acc[ns] = (f32x4){0.f,0.f,0.f,0.f};
  async_copy16(gA, &sA[0][w * 512]);
  async_copy16(gB0, &sB[0][(w * 2 + 0) * 512]);
  async_copy16(gB1, &sB[0][(w * 2 + 1) * 512]);
  for (int c = 0; c < 48; ++c) {
    __syncthreads();
    if (c + 1 < 48) {
      int nb = (c + 1) & 1, cc = c + 1;
      int offA = (cc < 16) ? cc * 32 : cc * 32 - 512;    // weights: (hi,hi,lo)
      int offB = (cc < 32) ? cc * 32 : cc * 32 - 1024;   // B slab:  (hi,lo,hi)
      async_copy16(gA + offA, &sA[nb][w * 512]);
      async_copy16(gB0 + offB, &sB[nb][(w * 2 + 0) * 512]);
      async_copy16(gB1 + offB, &sB[nb][(w * 2 + 1) * 512]);
    }
    const u16* bufA = sA[c & 1];
    const u16* bufB = sB[c & 1];
    bf16x8v av = *(const bf16x8v*)&bufA[(w * 16 + lan) * 32 + qs * 8];
#pragma unroll
    for (int ns = 0; ns < 8; ++ns) {
      bf16x8v bv = *(const bf16x8v*)&bufB[(ns * 16 + lan) * 32 + qs * 8];
      acc[ns] = mfma_bf(av, bv, acc[ns]);
    }
  }
#pragma unroll
  for (int ns = 0; ns < 8; ++ns) {
    int col = nB0 + ns * 16 + lan;
    int m0 = mB + w * 16 + quad * 4;
    f16x4v rv;
#pragma unroll
    for (int reg = 0; reg < 4; ++reg) {
      int m = m0 + reg;
      float v = acc[ns][reg] + ((m < NH2) ? av_b1[m] : 0.f);
      rv[reg] = (_Float16)(v > 0.f ? v : 0.f);
    }
    *(f16x4v*)&t1[(size_t)col * 1024 + m0] = rv;
  }
}

__global__ __launch_bounds__(256) void kSoft(const _Float16* __restrict__ t1,
                                             const float* __restrict__ av_w2,
                                             const float* __restrict__ av_b2,
                                             float* __restrict__ out1) {
  const int t = threadIdx.x, w = t >> 6, l = t & 63;
  int col = blockIdx.x * 4 + w;
  const _Float16* trow = t1 + (size_t)col * 1024;
  float s[8] = {};
  for (int i = 0; i < 16; ++i) {
    int k = i * 64 + l;
    if (k < NH2) {
      float v = (float)trow[k];
#pragma unroll
      for (int c = 0; c < 8; ++c) s[c] += v * av_w2[c * NH2 + k];
    }
  }
#pragma unroll
  for (int c = 0; c < 8; ++c) {
    s[c] += __shfl_xor(s[c], 32);
    s[c] += __shfl_xor(s[c], 16);
    s[c] += __shfl_xor(s[c], 8);
    s[c] += __shfl_xor(s[c], 4);
    s[c] += __shfl_xor(s[c], 2);
    s[c] += __shfl_xor(s[c], 1);
  }
  if (l == 0) {
    float lg[8], mx = -1e30f;
#pragma unroll
    for (int c = 0; c < 8; ++c) { lg[c] = s[c] + av_b2[c]; mx = fmaxf(mx, lg[c]); }
    float den = 0.f;
#pragma unroll
    for (int c = 0; c < 8; ++c) den += __expf(lg[c] - mx);
    int idx = col >> 8, b = col & 255;
#pragma unroll
    for (int c = 0; c < 8; ++c)
      out1[(b * NS + idx) * NC + c] = __expf(lg[c] - mx) / den;
  }
}

// ---------------- host ----------------

extern "C" void kernel_launch(void* const* d_in, const int* in_sizes, int n_in,
                              void* d_out, int out_size, void* d_ws, size_t ws_size,
                              hipStream_t stream) {
  (void)in_sizes; (void)n_in; (void)out_size; (void)ws_size;
  const float* z      = (const float*)d_in[0];
  const float* dep    = (const float*)d_in[1];
  const float* ne     = (const float*)d_in[2];
  const float* lin1_w = (const float*)d_in[3];
  const float* lin1_b = (const float*)d_in[4];
  const float* av_w1  = (const float*)d_in[5];
  const float* av_b1  = (const float*)d_in[6];
  const float* av_w2  = (const float*)d_in[7];
  const float* av_b2  = (const float*)d_in[8];
  const float* ae_w1  = (const float*)d_in[9];
  const float* ae_b1  = (const float*)d_in[10];
  const float* ae_w2  = (const float*)d_in[11];
  const float* ae_b2  = (const float*)d_in[12];
  const float* gate_w = (const float*)d_in[13];
  const float* gate_b = (const float*)d_in[14];
  const float* map_w  = (const float*)d_in[15];
  const float* map_b  = (const float*)d_in[16];
  const float* w_ih   = (const float*)d_in[17];
  const float* w_hh   = (const float*)d_in[18];
  const float* b_ih   = (const float*)d_in[19];
  const float* b_hh   = (const float*)d_in[20];

  float* out0 = (float*)d_out;
  float* out1 = out0 + NB * NS * NS;

  const size_t SLOT = (size_t)NB * KP;   // u16 elems per trio slab (2-seg)
  char* p = (char*)d_ws;
  // trio slabs: 0..7 = GS (graph_state at index i); 8 = hinT; 9,10 = hv scratch
  u16* trio = (u16*)p;            p += 11 * SLOT * 2;
  _Float16* Xe = (_Float16*)p;    p += (size_t)28 * NB * KE * 2;
  _Float16* Xn = (_Float16*)p;    p += (size_t)7 * NB * KE * 2;
  u16* Wgm  = (u16*)p;            p += (size_t)1024 * KP * 2;
  u16* Whh  = (u16*)p;            p += (size_t)1536 * KP * 2;
  u16* Wav1 = (u16*)p;            p += (size_t)1024 * KP * 2;
  _Float16* Wlr = (_Float16*)p;   p += (size_t)2048 * KA * 2;
  _Float16* t1 = (_Float16*)p;    p += (size_t)2048 * 1024 * 2;
  float* Pc   = (float*)p;        p += (size_t)8 * HV * 4;
  float* Qc   = (float*)p;        p += (size_t)8 * HV * 4;
  float* RS   = (float*)p;        p += (size_t)HV * 4;
  float* g0   = (float*)p;        p += (size_t)HV * 4;
  float* giN  = (float*)p;        p += (size_t)8 * NH3 * NB * 4;
  float* giT  = (float*)p;        p += (size_t)8 * NB * KG * 4;

  u16* hinT = trio + 8 * SLOT;

  // init (2 launches)
  kPack<<<5632, 256, 0, stream>>>(gate_w, map_w, w_hh, av_w1, ae_w1, Wgm, Whh, Wav1, Wlr);
  kInit<<<617, 256, 0, stream>>>(out0, ae_b2, trio, Xe, Xn,
                                 z, lin1_w, lin1_b, g0, ne, w_ih, b_ih, giN, giT);

  // index 0: hv = gru(x0, graph_state0); final -> GS1 + Xn0
  kHHw<<<256, 512, 0, stream>>>(Whh, trio, g0, giN, b_hh,
                                trio + 1 * SLOT, nullptr, Xn);

  for (int i = 0; i <= 6; ++i) {
    int index = i + 1;
    int sid0 = index * (index - 1) / 2;
    const float* gi_i = giN + (size_t)index * NH3 * NB;
    // transition: Pc/Qc[i] from GS[i+1]; first-inner-step hin + RS; hv0 -> Xe
    kGMT<<<256, 512, 0, stream>>>(Wgm, trio + (size_t)(i + 1) * SLOT,
                                  Pc + (size_t)i * HV, Qc + (size_t)i * HV,
                                  dep, gate_b, map_b, RS, hinT, giT, b_hh,
                                  Xe + (size_t)sid0 * NB * KE, index);
    // first HH of this outer step (inner j = index-1)
    bool final1 = (index == 1);
    u16* dst = final1 ? (trio + 2 * SLOT) : (trio + 9 * SLOT);
    kHHw<<<256, 512, 0, stream>>>(Whh, hinT, nullptr, gi_i, b_hh, dst,
        (index - 1 > 0) ? (Xe + (size_t)(sid0 + 1) * NB * KE) : nullptr,
        final1 ? (Xn + (size_t)1 * NB * KE) : nullptr);
    u16* prev = dst;
    int par = 1;
    for (int j = index - 2; j >= 0; --j) {
      kGM0<<<256, 512, 0, stream>>>(Wgm, prev, dep, gate_b, map_b,
                                    Pc + (size_t)j * HV, Qc + (size_t)j * HV,
                                    RS, hinT, index, j);
      bool fin = (j == 0);
      u16* d2 = (fin && index <= 6) ? (trio + (size_t)(index + 1) * SLOT)
                                    : (trio + (size_t)(9 + par) * SLOT);
      kHHw<<<256, 512, 0, stream>>>(Whh, hinT, nullptr, gi_i, b_hh, d2,
          (j > 0) ? (Xe + (size_t)(sid0 + index - j) * NB * KE) : nullptr,
          (fin && index <= 6) ? (Xn + (size_t)index * NB * KE) : nullptr);
      prev = d2; par ^= 1;
    }
  }

  // deferred (3 launches)
  kLogA<<<dim3(16, 16), 256, 0, stream>>>(Wav1, trio, av_b1, t1);
  kSoft<<<512, 256, 0, stream>>>(t1, av_w2, av_b2, out1);
  kEdge<<<dim3(16, 56), 256, 0, stream>>>(Wlr, Xe, Xn, ae_b1, ae_w2, out0);
}